// Round 11
// baseline (685.963 us; speedup 1.0000x reference)
//
#include <hip/hip_runtime.h>

#define NN 50000
#define NE 800000
#define FF 128
#define KF 8
#define DD 16
#define GG 512
#define BN_EPS 1e-5f
#define NB 196   // ceil(NN/256)
#define KSTR 264 // padded k-block stride for block-diag weights (flat staging)
#define BSTR 20  // padded per-16-col block stride (floats) in aggbd As/Ts

using s8v = __attribute__((ext_vector_type(8))) short;
using f4v = __attribute__((ext_vector_type(4))) float;
using h4v = __attribute__((ext_vector_type(4))) _Float16;
using h8v = __attribute__((ext_vector_type(8))) _Float16;
typedef unsigned int u32;

// async global->LDS, 16B per lane; LDS dest = wave-uniform base + lane*16 (m104),
// global src is PER-LANE (m173) -> swizzled layouts via pre-swizzled source address.
__device__ __forceinline__ void gload_lds16(const void* g, void* l) {
    __builtin_amdgcn_global_load_lds((const __attribute__((address_space(1))) u32*)g,
                                     (__attribute__((address_space(3))) u32*)l, 16, 0, 0);
}

// ---------------- CSR build ----------------
__global__ void k_deg(const int* __restrict__ dst, int* __restrict__ deg) {
    int e = blockIdx.x * 256 + threadIdx.x;
    if (e < NE) atomicAdd(&deg[dst[e]], 1);
}

__global__ __launch_bounds__(256) void k_bsum(const int* __restrict__ deg, int* __restrict__ bsum) {
    int idx = blockIdx.x * 256 + threadIdx.x;
    int v = (idx < NN) ? deg[idx] : 0;
#pragma unroll
    for (int off = 32; off; off >>= 1) v += __shfl_down(v, off, 64);
    __shared__ int ws[4];
    if ((threadIdx.x & 63) == 0) ws[threadIdx.x >> 6] = v;
    __syncthreads();
    if (threadIdx.x == 0) bsum[blockIdx.x] = ws[0] + ws[1] + ws[2] + ws[3];
}

__global__ __launch_bounds__(256) void k_bscan(const int* __restrict__ bsum, int* __restrict__ boffs) {
    __shared__ int s[256];
    int tid = threadIdx.x;
    int v = (tid < NB) ? bsum[tid] : 0;
    s[tid] = v;
    __syncthreads();
    for (int off = 1; off < 256; off <<= 1) {
        int t = (tid >= off) ? s[tid - off] : 0;
        __syncthreads();
        s[tid] += t;
        __syncthreads();
    }
    if (tid < NB) boffs[tid] = s[tid] - v;  // exclusive
}

__global__ __launch_bounds__(256) void k_offs(const int* __restrict__ deg,
                                              const int* __restrict__ boffs,
                                              int* __restrict__ offs) {
    __shared__ int s[256];
    int tid = threadIdx.x;
    int idx = blockIdx.x * 256 + tid;
    int v = (idx < NN) ? deg[idx] : 0;
    s[tid] = v;
    __syncthreads();
    for (int off = 1; off < 256; off <<= 1) {
        int t = (tid >= off) ? s[tid - off] : 0;
        __syncthreads();
        s[tid] += t;
        __syncthreads();
    }
    int incl = s[tid];
    if (idx < NN) offs[idx] = boffs[blockIdx.x] + incl - v;
    if (idx == NN - 1) offs[NN] = boffs[blockIdx.x] + incl;
}

__global__ void k_fill(const int* __restrict__ src, const int* __restrict__ dst,
                       const int* __restrict__ offs, int* __restrict__ cnt,
                       int* __restrict__ csr) {
    int e = blockIdx.x * 256 + threadIdx.x;
    if (e < NE) {
        int d = dst[e];
        int p = atomicAdd(&cnt[d], 1);
        csr[offs[d] + p] = src[e];
    }
}

// ---------------- helpers ----------------
__device__ __forceinline__ void bn_coefs(const float* st, const float* g, const float* be,
                                         int lane, float4& a4, float4& b4) {
    const float inv_n = 1.0f / (float)NN;
    float av[4], bv[4];
#pragma unroll
    for (int t = 0; t < 4; t++) {
        int c = lane * 4 + t;
        float mu = st[c] * inv_n;
        float var = st[FF + c] * inv_n - mu * mu;
        float a = g[c] * rsqrtf(var + BN_EPS);
        av[t] = a;
        bv[t] = be[c] - mu * a;
    }
    a4 = make_float4(av[0], av[1], av[2], av[3]);
    b4 = make_float4(bv[0], bv[1], bv[2], bv[3]);
}

__device__ __forceinline__ float4 h2f(h4v h) {
    return make_float4((float)h.x, (float)h.y, (float)h.z, (float)h.w);
}

// ---------------- fp32 -> fp16 one-shot convert of the input x ----------------
__global__ __launch_bounds__(256) void k_cvt(const float4* __restrict__ X, h4v* __restrict__ O) {
    int i = blockIdx.x * 256 + threadIdx.x;  // over NN*32
    if (i < NN * 32) {
        float4 v = X[i];
        h4v o;
        o.x = (_Float16)v.x; o.y = (_Float16)v.y;
        o.z = (_Float16)v.z; o.w = (_Float16)v.w;
        O[i] = o;
    }
}

// ---------------- weight prep: fp32 [l][k][n] -> fp16 W^T [n][k] (single plane) ----
__global__ __launch_bounds__(256) void k_wprep(const float* __restrict__ W1,
                                               const float* __restrict__ W2,
                                               unsigned short* __restrict__ out) {
    int idx = blockIdx.x * 256 + threadIdx.x;  // over 3*2*16384
    if (idx >= 3 * 2 * 16384) return;
    int l = idx / (2 * 16384);
    int rem = idx % (2 * 16384);
    int mat = rem >> 14;
    int e = rem & 16383;
    int n = e >> 7, k = e & 127;
    const float* W = (mat == 0) ? (W1 + (size_t)l * 16384) : (W2 + (size_t)l * 16384);
    float v = W[k * 128 + n];
    _Float16* o = (_Float16*)out + (size_t)(l * 2 + mat) * 16384;
    o[n * 128 + k] = (_Float16)v;
}

// ---------------- weight prep for h0: Wcat^T (slot 6) + blockdiag(W2)^T (slot 7) ---
__global__ __launch_bounds__(256) void k_wprep_h0(const float* __restrict__ W1,  // [K,F,d]
                                                  const float* __restrict__ W2,  // [K,d,d]
                                                  unsigned short* __restrict__ out) {
    int idx = blockIdx.x * 256 + threadIdx.x;  // over 2*16384
    if (idx >= 2 * 16384) return;
    int mat = idx >> 14;
    int e = idx & 16383;
    int n = e >> 7, k = e & 127;
    float v;
    if (mat == 0) {
        v = W1[(n >> 4) * (FF * DD) + k * DD + (n & 15)];
    } else {
        v = ((k >> 4) == (n >> 4)) ? W2[(n >> 4) * 256 + (k & 15) * DD + (n & 15)] : 0.f;
    }
    _Float16* o = (_Float16*)out + (size_t)(6 + mat) * 16384;
    o[n * 128 + k] = (_Float16)v;
}

// ---------------- column-sliced aggregation (R11) ----------------
// 4 col-slices of 32 cols; slice = blockIdx & 3. With round-robin block->XCD
// dispatch, XCD x sees only slice x%4 -> per-XCD gather working set 3.2MB (L2-
// resident) instead of the full 12.8MB (60% hit). Group = 32 lanes = 4 edge-slots
// x 8 lanes (8B/lane = 32 cols). Cross-slot merge: shfl_xor(8,16); sub==0 lanes
// add self + store. BN&&!RELU folds to post-sum affine (linear).
template <bool BN, bool RELU>
__global__ __launch_bounds__(256) void k_agg(const h4v* __restrict__ X,
                                             const int* __restrict__ offs,
                                             const int* __restrict__ csr,
                                             const float* __restrict__ st,
                                             const float* __restrict__ g,
                                             const float* __restrict__ be,
                                             h4v* __restrict__ Zh) {
    int slice = blockIdx.x & 3;
    int nodeblk = blockIdx.x >> 2;
    int grp = threadIdx.x >> 5;
    int lane = threadIdx.x & 31;
    int sub = lane >> 3;   // edge slot 0..3
    int li = lane & 7;     // 8B chunk within slice
    int n = nodeblk * 8 + grp;
    int colbase = slice * 8 + li;  // h4v index within a 32-h4v row

    float4 a4 = make_float4(1.f, 1.f, 1.f, 1.f);
    float4 b4 = make_float4(0.f, 0.f, 0.f, 0.f);
    if (BN) {
        const float inv_n = 1.0f / (float)NN;
        float av[4], bv[4];
#pragma unroll
        for (int t = 0; t < 4; t++) {
            int c = slice * 32 + li * 4 + t;
            float mu = st[c] * inv_n;
            float var = st[FF + c] * inv_n - mu * mu;
            float a = g[c] * rsqrtf(var + BN_EPS);
            av[t] = a;
            bv[t] = be[c] - mu * a;
        }
        a4 = make_float4(av[0], av[1], av[2], av[3]);
        b4 = make_float4(bv[0], bv[1], bv[2], bv[3]);
    }

    // per-element transform inside the sum: only the BN+RELU case is nonlinear
    auto apply = [&](float4 v) -> float4 {
        if (BN && RELU) {
            v.x = fmaxf(fmaf(v.x, a4.x, b4.x), 0.f);
            v.y = fmaxf(fmaf(v.y, a4.y, b4.y), 0.f);
            v.z = fmaxf(fmaf(v.z, a4.z, b4.z), 0.f);
            v.w = fmaxf(fmaf(v.w, a4.w, b4.w), 0.f);
        }
        return v;
    };

    float4 acc = make_float4(0.f, 0.f, 0.f, 0.f);
    auto add4 = [](float4& a, float4 b) {
        a.x += b.x; a.y += b.y; a.z += b.z; a.w += b.w;
    };

    int e0 = offs[n], e1 = offs[n + 1];
    int e = e0;
    int i0, i1;
    if (e + 8 <= e1) {
        i0 = csr[e + sub];
        i1 = csr[e + 4 + sub];
    }
    while (e + 8 <= e1) {
        h4v r0 = X[(size_t)i0 * 32 + colbase];
        h4v r1 = X[(size_t)i1 * 32 + colbase];
        e += 8;
        // prefetch next batch's indices (reads past e1 land in adjacent ws region)
        int t0 = csr[e + sub];
        int t1 = csr[e + 4 + sub];
        add4(acc, apply(h2f(r0)));
        add4(acc, apply(h2f(r1)));
        i0 = t0; i1 = t1;
    }
    for (; e < e1; e += 4) {
        if (e + sub < e1) {
            int q = csr[e + sub];
            add4(acc, apply(h2f(X[(size_t)q * 32 + colbase])));
        }
    }

    // merge the 4 edge-slots (butterfly within the 32-lane group)
    acc.x += __shfl_xor(acc.x, 8);  acc.y += __shfl_xor(acc.y, 8);
    acc.z += __shfl_xor(acc.z, 8);  acc.w += __shfl_xor(acc.w, 8);
    acc.x += __shfl_xor(acc.x, 16); acc.y += __shfl_xor(acc.y, 16);
    acc.z += __shfl_xor(acc.z, 16); acc.w += __shfl_xor(acc.w, 16);

    if (sub == 0) {
        float4 self = h2f(X[(size_t)n * 32 + colbase]);
        float4 fin;
        if (BN && RELU) {
            add4(acc, apply(self));
            fin = acc;
        } else if (BN) {  // linear: affine fold on the raw sum (incl self)
            add4(acc, self);
            float cnt = (float)(e1 - e0 + 1);
            fin.x = fmaf(acc.x, a4.x, cnt * b4.x);
            fin.y = fmaf(acc.y, a4.y, cnt * b4.y);
            fin.z = fmaf(acc.z, a4.z, cnt * b4.z);
            fin.w = fmaf(acc.w, a4.w, cnt * b4.w);
        } else {
            add4(acc, self);
            fin = acc;
        }
        h4v o;
        o.x = (_Float16)fin.x; o.y = (_Float16)fin.y;
        o.z = (_Float16)fin.z; o.w = (_Float16)fin.w;
        Zh[(size_t)n * 32 + colbase] = o;
    }
}

// ============ fp16 MFMA GEMM pair (R9, unchanged) ============
__global__ __launch_bounds__(256) void gemm_mfma(const _Float16* __restrict__ A,
                                                 const unsigned short* __restrict__ W1T,
                                                 const unsigned short* __restrict__ W2T,
                                                 const float* __restrict__ b1,
                                                 const float* __restrict__ b2,
                                                 _Float16* __restrict__ C,
                                                 float* __restrict__ stout) {
    __shared__ __align__(16) unsigned short Zs[8192];   // A/z fp16 [64][256B], 16KB
    __shared__ __align__(16) unsigned short Wch[8192];  // W chunk dbuf 2 x 8KB
    __shared__ float Sred[1024];                        // 4KB stats scratch
    int tid = threadIdx.x;
    int row0 = blockIdx.x * 64;
    int w = tid >> 6, lane = tid & 63, quad = lane >> 4, lid = lane & 15;

    // ---- per-thread W-stage source offsets (halfs, sans kc); 8KB chunk, 2/wave ----
    int wsrc[2], wdst[2];
#pragma unroll
    for (int i = 0; i < 2; i++) {
        int L = (w * 2 + i) * 1024 + lane * 16;  // byte within 8KB chunk image
        int npair = L >> 7, cc = L & 127;
        int ccp = cc ^ ((npair & 7) << 4);
        wsrc[i] = (npair * 2 + (ccp >> 6)) * 128 + ((ccp & 63) >> 1);
        wdst[i] = (w * 2 + i) * 1024;            // wave-uniform LDS byte base
    }

    // ---- stage A fp16 plane into Zs (global src pre-swizzled); 16KB, 4/wave ----
#pragma unroll
    for (int i = 0; i < 4; i++) {
        int L = (w * 4 + i) * 1024 + lane * 16;
        int row = L >> 8, cb = L & 255;
        int cbp = cb ^ ((row & 7) << 4);
        int grow = row0 + row;
        if (grow >= NN) grow = NN - 1;
        gload_lds16((const char*)A + (size_t)grow * 256 + cbp,
                    (char*)Zs + (w * 4 + i) * 1024);
    }
    // ---- stage W1 chunk 0 into buf 0 ----
#pragma unroll
    for (int i = 0; i < 2; i++)
        gload_lds16(W1T + wsrc[i], (char*)Wch + wdst[i]);
    __syncthreads();

    // ---- per-thread read-address precompute ----
    int lr = w * 16 + lid;
    int swzr = (lr & 7) << 4;
    int abase = lr * 256;  // byte within Zs
    int boff[8];
#pragma unroll
    for (int n0 = 0; n0 < 8; n0++) {
        int nn = n0 * 16 + lid;
        int cc = ((nn & 1) << 6) | (quad << 4);
        boff[n0] = (nn >> 1) * 128 + (cc ^ (((nn >> 1) & 7) << 4));
    }

    f4v acc[8];
#pragma unroll
    for (int i = 0; i < 8; i++) acc[i] = 0;

    // ---- unified 8-chunk loop: g 0..3 = phase 1 (W1), 4..7 = phase 2 (W2) ----
    for (int g = 0; g < 8; ++g) {
        int buf = g & 1;
        if (g < 7) {  // issue next chunk's stage first (overlaps with compute below)
            const unsigned short* WT = (g + 1 < 4) ? W1T : W2T;
            int kcn = (g + 1) & 3;
#pragma unroll
            for (int i = 0; i < 2; i++)
                gload_lds16(WT + wsrc[i] + kcn * 32,
                            (char*)Wch + (buf ^ 1) * 8192 + wdst[i]);
        }
        int kc = g & 3;
        int aoff = (kc * 64 + quad * 16) ^ swzr;
        h8v a = *(const h8v*)((const char*)Zs + abase + aoff);
        const char* wb = (const char*)Wch + buf * 8192;
#pragma unroll
        for (int n0 = 0; n0 < 8; n0++) {
            h8v b = *(const h8v*)(wb + boff[n0]);
            acc[n0] = __builtin_amdgcn_mfma_f32_16x16x32_f16(a, b, acc[n0], 0, 0, 0);
        }
        if (g == 3) {
            // z = relu(acc+b1) -> overwrite Zs (wave-local rows), same swizzled layout
#pragma unroll
            for (int n0 = 0; n0 < 8; n0++) {
                int c = n0 * 16 + lid;
                float bb = b1[c];
#pragma unroll
                for (int rr = 0; rr < 4; rr++) {
                    int zr = w * 16 + quad * 4 + rr;
                    float z = fmaxf(acc[n0][rr] + bb, 0.f);
                    int zb = zr * 256 + ((2 * c) ^ ((zr & 7) << 4));
                    *(_Float16*)((char*)Zs + zb) = (_Float16)z;
                }
                acc[n0] = 0;
            }
        }
        if (g < 7) __syncthreads();  // drains next-chunk stage; orders buffer reuse
    }

    // ---- epilogue: bias, fp16 store, stats (stats from fp32 register values) ----
#pragma unroll
    for (int n0 = 0; n0 < 8; n0++) {
        int c = n0 * 16 + lid;
        float bb = b2[c];
        float s = 0.f, q = 0.f;
#pragma unroll
        for (int rr = 0; rr < 4; rr++) {
            int grow = row0 + w * 16 + quad * 4 + rr;
            if (grow < NN) {
                float v = acc[n0][rr] + bb;
                C[(size_t)grow * 128 + c] = (_Float16)v;
                s += v;
                q += v * v;
            }
        }
        s += __shfl_xor(s, 16); s += __shfl_xor(s, 32);
        q += __shfl_xor(q, 16); q += __shfl_xor(q, 32);
        if (quad == 0) {
            Sred[w * 128 + c] = s;
            Sred[512 + w * 128 + c] = q;
        }
    }
    __syncthreads();
    if (tid < 128) {
        float s = Sred[tid] + Sred[128 + tid] + Sred[256 + tid] + Sred[384 + tid];
        float q = Sred[512 + tid] + Sred[640 + tid] + Sred[768 + tid] + Sred[896 + tid];
        atomicAdd(&stout[tid], s);
        atomicAdd(&stout[FF + tid], q);
    }
}

// ---------------- fused h1: agg (R9 layout + index prefetch) + block-diag MLP ------
__global__ __launch_bounds__(256) void k_aggbd(const h4v* __restrict__ X,
                                               const int* __restrict__ offs,
                                               const int* __restrict__ csr,
                                               const float* __restrict__ st,
                                               const float* __restrict__ g,
                                               const float* __restrict__ be,
                                               const float* __restrict__ W1,
                                               const float4* __restrict__ b1,
                                               const float* __restrict__ W2,
                                               const float4* __restrict__ b2,
                                               float4* __restrict__ C) {
    __shared__ float As[8][8 * BSTR];
    __shared__ float Ts[8][8 * BSTR];
    __shared__ float Ws1[KF * KSTR];
    __shared__ float Ws2[KF * KSTR];
    int grp = threadIdx.x >> 5, lane = threadIdx.x & 31;
    int n = blockIdx.x * 8 + grp;

    for (int l = threadIdx.x; l < KF * 256; l += 256) {
        int k = l >> 8, r = l & 255;
        Ws1[k * KSTR + r] = W1[l];
        Ws2[k * KSTR + r] = W2[l];
    }

    float4 a4, b4;
    bn_coefs(st, g, be, lane, a4, b4);
    auto apply = [&](float4 v) -> float4 {
        v.x = fmaxf(fmaf(v.x, a4.x, b4.x), 0.f);
        v.y = fmaxf(fmaf(v.y, a4.y, b4.y), 0.f);
        v.z = fmaxf(fmaf(v.z, a4.z, b4.z), 0.f);
        v.w = fmaxf(fmaf(v.w, a4.w, b4.w), 0.f);
        return v;
    };
    auto add4 = [](float4& a, float4 b) {
        a.x += b.x; a.y += b.y; a.z += b.z; a.w += b.w;
    };

    float4 acc = apply(h2f(X[(size_t)n * 32 + lane]));
    int e0 = offs[n], e1 = offs[n + 1];
    int e = e0;
    int s0, s1, s2, s3, s4, s5, s6, s7;
    if (e + 8 <= e1) {
        s0 = csr[e]; s1 = csr[e + 1]; s2 = csr[e + 2]; s3 = csr[e + 3];
        s4 = csr[e + 4]; s5 = csr[e + 5]; s6 = csr[e + 6]; s7 = csr[e + 7];
    }
    while (e + 8 <= e1) {
        h4v r0 = X[(size_t)s0 * 32 + lane];
        h4v r1 = X[(size_t)s1 * 32 + lane];
        h4v r2 = X[(size_t)s2 * 32 + lane];
        h4v r3 = X[(size_t)s3 * 32 + lane];
        h4v r4 = X[(size_t)s4 * 32 + lane];
        h4v r5 = X[(size_t)s5 * 32 + lane];
        h4v r6 = X[(size_t)s6 * 32 + lane];
        h4v r7 = X[(size_t)s7 * 32 + lane];
        e += 8;
        int t0 = csr[e], t1 = csr[e + 1], t2 = csr[e + 2], t3 = csr[e + 3];
        int t4 = csr[e + 4], t5 = csr[e + 5], t6 = csr[e + 6], t7 = csr[e + 7];
        float4 v0 = apply(h2f(r0));
        float4 v1 = apply(h2f(r1));
        float4 v2 = apply(h2f(r2));
        float4 v3 = apply(h2f(r3));
        float4 v4 = apply(h2f(r4));
        float4 v5 = apply(h2f(r5));
        float4 v6 = apply(h2f(r6));
        float4 v7 = apply(h2f(r7));
        add4(v0, v1); add4(v2, v3); add4(v4, v5); add4(v6, v7);
        add4(v0, v2); add4(v4, v6); add4(v0, v4); add4(acc, v0);
        s0 = t0; s1 = t1; s2 = t2; s3 = t3;
        s4 = t4; s5 = t5; s6 = t6; s7 = t7;
    }
    for (; e + 4 <= e1; e += 4) {
        int q0 = csr[e], q1 = csr[e + 1], q2 = csr[e + 2], q3 = csr[e + 3];
        float4 v0 = apply(h2f(X[(size_t)q0 * 32 + lane]));
        float4 v1 = apply(h2f(X[(size_t)q1 * 32 + lane]));
        float4 v2 = apply(h2f(X[(size_t)q2 * 32 + lane]));
        float4 v3 = apply(h2f(X[(size_t)q3 * 32 + lane]));
        add4(v0, v1); add4(v2, v3); add4(v0, v2); add4(acc, v0);
    }
    for (; e < e1; e++) {
        float4 v = apply(h2f(X[(size_t)csr[e] * 32 + lane]));
        add4(acc, v);
    }
    // store agg result (cols lane*4..+3) into padded layout
    *(float4*)&As[grp][(lane >> 2) * BSTR + (lane & 3) * 4] = acc;
    __syncthreads();

    int k = lane >> 2, jb = (lane & 3) * 4;
    float a[16];
    {
        const float4* As4 = (const float4*)&As[grp][k * BSTR];
        float4 a0 = As4[0], a1 = As4[1], a2 = As4[2], a3 = As4[3];
        a[0] = a0.x; a[1] = a0.y; a[2] = a0.z; a[3] = a0.w;
        a[4] = a1.x; a[5] = a1.y; a[6] = a1.z; a[7] = a1.w;
        a[8] = a2.x; a[9] = a2.y; a[10] = a2.z; a[11] = a2.w;
        a[12] = a3.x; a[13] = a3.y; a[14] = a3.z; a[15] = a3.w;
    }
    const float* wp1 = &Ws1[k * KSTR + jb];
    float4 t = b1[lane];
#pragma unroll
    for (int i = 0; i < 16; i++) {
        float4 wv = *(const float4*)&wp1[i * 16];
        t.x = fmaf(a[i], wv.x, t.x);
        t.y = fmaf(a[i], wv.y, t.y);
        t.z = fmaf(a[i], wv.z, t.z);
        t.w = fmaf(a[i], wv.w, t.w);
    }
    t.x = fmaxf(t.x, 0.f); t.y = fmaxf(t.y, 0.f);
    t.z = fmaxf(t.z, 0.f); t.w = fmaxf(t.w, 0.f);
    *(float4*)&Ts[grp][(lane >> 2) * BSTR + (lane & 3) * 4] = t;
    __syncthreads();

    float b[16];
    {
        const float4* Ts4 = (const float4*)&Ts[grp][k * BSTR];
        float4 a0 = Ts4[0], a1 = Ts4[1], a2 = Ts4[2], a3 = Ts4[3];
        b[0] = a0.x; b[1] = a0.y; b[2] = a0.z; b[3] = a0.w;
        b[4] = a1.x; b[5] = a1.y; b[6] = a1.z; b[7] = a1.w;
        b[8] = a2.x; b[9] = a2.y; b[10] = a2.z; b[11] = a2.w;
        b[12] = a3.x; b[13] = a3.y; b[14] = a3.z; b[15] = a3.w;
    }
    const float* wp2 = &Ws2[k * KSTR + jb];
    float4 acc2 = b2[lane];
#pragma unroll
    for (int i = 0; i < 16; i++) {
        float4 wv = *(const float4*)&wp2[i * 16];
        acc2.x = fmaf(b[i], wv.x, acc2.x);
        acc2.y = fmaf(b[i], wv.y, acc2.y);
        acc2.z = fmaf(b[i], wv.z, acc2.z);
        acc2.w = fmaf(b[i], wv.w, acc2.w);
    }
    C[(size_t)n * 32 + lane] = acc2;
}

// ---------------- BN stats (standalone, for k_aggbd output) ----------------
__global__ __launch_bounds__(256) void k_stats(const float* __restrict__ X,
                                               float* __restrict__ st, int nrows) {
    int c = threadIdx.x & 127;
    int half = threadIdx.x >> 7;
    int rpb = (nrows + gridDim.x - 1) / gridDim.x;
    int r0 = blockIdx.x * rpb;
    int r1 = min(r0 + rpb, nrows);
    float s = 0.f, sq = 0.f;
    for (int r = r0 + half; r < r1; r += 2) {
        float v = X[(size_t)r * FF + c];
        s += v;
        sq += v * v;
    }
    atomicAdd(&st[c], s);
    atomicAdd(&st[FF + c], sq);
}

// ---------------- pooling with fused final BN ----------------
__global__ __launch_bounds__(128) void k_pool(const float* __restrict__ X,
                                              const int* __restrict__ batch,
                                              const float* __restrict__ st,
                                              const float* __restrict__ g,
                                              const float* __restrict__ be,
                                              float* __restrict__ out) {
    int c = threadIdx.x;
    const float inv_n = 1.0f / (float)NN;
    float mu = st[c] * inv_n;
    float var = st[FF + c] * inv_n - mu * mu;
    float a = g[c] * rsqrtf(var + BN_EPS);
    float b = be[c] - mu * a;
    int chunk = (NN + gridDim.x - 1) / gridDim.x;
    int r0 = blockIdx.x * chunk;
    int r1 = min(r0 + chunk, NN);
    if (r0 >= r1) return;
    float acc = 0.f;
    int cnt = 0;
    int cur = batch[r0];
    for (int r = r0; r < r1; r++) {
        int bb = batch[r];
        if (bb != cur) {
            atomicAdd(&out[(size_t)cur * FF + c], fmaf(a, acc, b * (float)cnt));
            acc = 0.f;
            cnt = 0;
            cur = bb;
        }
        acc += X[(size_t)r * FF + c];
        cnt++;
    }
    atomicAdd(&out[(size_t)cur * FF + c], fmaf(a, acc, b * (float)cnt));
}

extern "C" void kernel_launch(void* const* d_in, const int* in_sizes, int n_in,
                              void* d_out, int out_size, void* d_ws, size_t ws_size,
                              hipStream_t stream) {
    const float* x = (const float*)d_in[0];
    const int* ei = (const int*)d_in[1];
    const int* src = ei;
    const int* dst = ei + NE;
    const int* batch = (const int*)d_in[2];
    const float* gc_W1 = (const float*)d_in[4];
    const float* gc_b1 = (const float*)d_in[5];
    const float* gc_W2 = (const float*)d_in[6];
    const float* gc_b2 = (const float*)d_in[7];
    const float* gc_g = (const float*)d_in[8];
    const float* gc_be = (const float*)d_in[9];
    const float* h0_W1 = (const float*)d_in[10];
    const float* h0_b1 = (const float*)d_in[11];
    const float* h0_W2 = (const float*)d_in[12];
    const float* h0_b2 = (const float*)d_in[13];
    const float* h0_g = (const float*)d_in[14];
    const float* h0_be = (const float*)d_in[15];
    const float* h1_W1 = (const float*)d_in[16];
    const float* h1_b1 = (const float*)d_in[17];
    const float* h1_W2 = (const float*)d_in[18];
    const float* h1_b2 = (const float*)d_in[19];
    const float* h1_g = (const float*)d_in[20];
    const float* h1_be = (const float*)d_in[21];

    const size_t NF = (size_t)NN * FF;
    float* P0 = (float*)d_ws;  // Zh fp16 plane (k_agg output / gemm A input)
    float* P1 = P0 + NF;       // Hbuf fp16 (gemm C output / gather input)
    float* P2 = P1 + NF;
    float* stats = P2 + NF;
    int* deg = (int*)(stats + 5 * 256);
    int* cnt = deg + NN;
    int* offs = cnt + NN;
    int* bsum = offs + (NN + 4);
    int* boffs = bsum + 256;
    int* csr = boffs + 256;
    unsigned short* wbf = (unsigned short*)(csr + NE);  // 8 slots x 16384 fp16

    h4v* Zh = (h4v*)P0;    // fp16 agg output, NN x 128
    h4v* Hbuf = (h4v*)P1;  // fp16 activations, NN x 128

    hipMemsetAsync(deg, 0, (size_t)2 * NN * sizeof(int), stream);
    hipMemsetAsync(stats, 0, 5 * 256 * sizeof(float), stream);
    hipMemsetAsync(d_out, 0, (size_t)GG * KF * DD * sizeof(float), stream);

    k_deg<<<(NE + 255) / 256, 256, 0, stream>>>(dst, deg);
    k_bsum<<<NB, 256, 0, stream>>>(deg, bsum);
    k_bscan<<<1, 256, 0, stream>>>(bsum, boffs);
    k_offs<<<NB, 256, 0, stream>>>(deg, boffs, offs);
    k_fill<<<(NE + 255) / 256, 256, 0, stream>>>(src, dst, offs, cnt, csr);
    k_wprep<<<(3 * 2 * 16384 + 255) / 256, 256, 0, stream>>>(gc_W1, gc_W2, wbf);
    k_wprep_h0<<<(2 * 16384 + 255) / 256, 256, 0, stream>>>(h0_W1, h0_W2, wbf);
    k_cvt<<<(NN * 32 + 255) / 256, 256, 0, stream>>>((const float4*)x, Hbuf);

    const int agg_grid = (NN / 8) * 4;      // 25000: (nodeblk << 2) | slice
    const int bd_grid = NN / 8;             // 6250
    const int gemm_grid = (NN + 63) / 64;   // 782

    // ---- GC layers: sliced agg(fp16 out) + fp16 MFMA gemm pair (stats fused) ----
    k_agg<false, false><<<agg_grid, 256, 0, stream>>>(
        Hbuf, offs, csr, nullptr, nullptr, nullptr, Zh);
    gemm_mfma<<<gemm_grid, 256, 0, stream>>>(
        (const _Float16*)Zh, wbf + 0 * 16384, wbf + 1 * 16384, gc_b1, gc_b2,
        (_Float16*)Hbuf, stats);

    k_agg<true, true><<<agg_grid, 256, 0, stream>>>(
        Hbuf, offs, csr, stats, gc_g, gc_be, Zh);
    gemm_mfma<<<gemm_grid, 256, 0, stream>>>(
        (const _Float16*)Zh, wbf + 2 * 16384, wbf + 3 * 16384, gc_b1 + FF, gc_b2 + FF,
        (_Float16*)Hbuf, stats + 256);

    k_agg<true, true><<<agg_grid, 256, 0, stream>>>(
        Hbuf, offs, csr, stats + 256, gc_g + FF, gc_be + FF, Zh);
    gemm_mfma<<<gemm_grid, 256, 0, stream>>>(
        (const _Float16*)Zh, wbf + 4 * 16384, wbf + 5 * 16384, gc_b1 + 2 * FF, gc_b2 + 2 * FF,
        (_Float16*)Hbuf, stats + 512);

    // ---- head layer 0: sliced agg (GC2 BN affine-folded) + fp16 MFMA ----
    k_agg<true, false><<<agg_grid, 256, 0, stream>>>(
        Hbuf, offs, csr, stats + 512, gc_g + 2 * FF, gc_be + 2 * FF, Zh);
    gemm_mfma<<<gemm_grid, 256, 0, stream>>>(
        (const _Float16*)Zh, wbf + 6 * 16384, wbf + 7 * 16384, h0_b1, h0_b2,
        (_Float16*)Hbuf, stats + 768);

    // ---- head layer 1: fused agg(BN+relu) + double block-diag MLP ----
    k_aggbd<<<bd_grid, 256, 0, stream>>>(
        Hbuf, offs, csr, stats + 768, h0_g, h0_be,
        h1_W1, (const float4*)h1_b1, h1_W2, (const float4*)h1_b2, (float4*)P2);
    k_stats<<<256, 256, 0, stream>>>(P2, stats + 1024, NN);

    // ---- pool with fused final BN ----
    k_pool<<<512, 128, 0, stream>>>(P2, batch, stats + 1024, h1_g, h1_be, (float*)d_out);
}

// Round 12
// 657.045 us; speedup vs baseline: 1.0440x; 1.0440x over previous
//
#include <hip/hip_runtime.h>

#define NN 50000
#define NE 800000
#define FF 128
#define KF 8
#define DD 16
#define GG 512
#define BN_EPS 1e-5f
#define NB 196   // ceil(NN/256)
#define KSTR 264 // padded k-block stride for block-diag weights (flat staging)
#define BSTR 20  // padded per-16-col block stride (floats) in aggbd As/Ts

using s8v = __attribute__((ext_vector_type(8))) short;
using f4v = __attribute__((ext_vector_type(4))) float;
using h4v = __attribute__((ext_vector_type(4))) _Float16;
using h8v = __attribute__((ext_vector_type(8))) _Float16;
typedef unsigned int u32;

// async global->LDS, 16B per lane; LDS dest = wave-uniform base + lane*16 (m104),
// global src is PER-LANE (m173) -> swizzled layouts via pre-swizzled source address.
__device__ __forceinline__ void gload_lds16(const void* g, void* l) {
    __builtin_amdgcn_global_load_lds((const __attribute__((address_space(1))) u32*)g,
                                     (__attribute__((address_space(3))) u32*)l, 16, 0, 0);
}

// ---------------- CSR build ----------------
__global__ void k_deg(const int* __restrict__ dst, int* __restrict__ deg) {
    int e = blockIdx.x * 256 + threadIdx.x;
    if (e < NE) atomicAdd(&deg[dst[e]], 1);
}

__global__ __launch_bounds__(256) void k_bsum(const int* __restrict__ deg, int* __restrict__ bsum) {
    int idx = blockIdx.x * 256 + threadIdx.x;
    int v = (idx < NN) ? deg[idx] : 0;
#pragma unroll
    for (int off = 32; off; off >>= 1) v += __shfl_down(v, off, 64);
    __shared__ int ws[4];
    if ((threadIdx.x & 63) == 0) ws[threadIdx.x >> 6] = v;
    __syncthreads();
    if (threadIdx.x == 0) bsum[blockIdx.x] = ws[0] + ws[1] + ws[2] + ws[3];
}

__global__ __launch_bounds__(256) void k_bscan(const int* __restrict__ bsum, int* __restrict__ boffs) {
    __shared__ int s[256];
    int tid = threadIdx.x;
    int v = (tid < NB) ? bsum[tid] : 0;
    s[tid] = v;
    __syncthreads();
    for (int off = 1; off < 256; off <<= 1) {
        int t = (tid >= off) ? s[tid - off] : 0;
        __syncthreads();
        s[tid] += t;
        __syncthreads();
    }
    if (tid < NB) boffs[tid] = s[tid] - v;  // exclusive
}

__global__ __launch_bounds__(256) void k_offs(const int* __restrict__ deg,
                                              const int* __restrict__ boffs,
                                              int* __restrict__ offs) {
    __shared__ int s[256];
    int tid = threadIdx.x;
    int idx = blockIdx.x * 256 + tid;
    int v = (idx < NN) ? deg[idx] : 0;
    s[tid] = v;
    __syncthreads();
    for (int off = 1; off < 256; off <<= 1) {
        int t = (tid >= off) ? s[tid - off] : 0;
        __syncthreads();
        s[tid] += t;
        __syncthreads();
    }
    int incl = s[tid];
    if (idx < NN) offs[idx] = boffs[blockIdx.x] + incl - v;
    if (idx == NN - 1) offs[NN] = boffs[blockIdx.x] + incl;
}

__global__ void k_fill(const int* __restrict__ src, const int* __restrict__ dst,
                       const int* __restrict__ offs, int* __restrict__ cnt,
                       int* __restrict__ csr) {
    int e = blockIdx.x * 256 + threadIdx.x;
    if (e < NE) {
        int d = dst[e];
        int p = atomicAdd(&cnt[d], 1);
        csr[offs[d] + p] = src[e];
    }
}

// ---------------- helpers ----------------
__device__ __forceinline__ void bn_coefs(const float* st, const float* g, const float* be,
                                         int lane, float4& a4, float4& b4) {
    const float inv_n = 1.0f / (float)NN;
    float av[4], bv[4];
#pragma unroll
    for (int t = 0; t < 4; t++) {
        int c = lane * 4 + t;
        float mu = st[c] * inv_n;
        float var = st[FF + c] * inv_n - mu * mu;
        float a = g[c] * rsqrtf(var + BN_EPS);
        av[t] = a;
        bv[t] = be[c] - mu * a;
    }
    a4 = make_float4(av[0], av[1], av[2], av[3]);
    b4 = make_float4(bv[0], bv[1], bv[2], bv[3]);
}

__device__ __forceinline__ float4 h2f(h4v h) {
    return make_float4((float)h.x, (float)h.y, (float)h.z, (float)h.w);
}

// ---------------- fp32 -> fp16 one-shot convert of the input x ----------------
__global__ __launch_bounds__(256) void k_cvt(const float4* __restrict__ X, h4v* __restrict__ O) {
    int i = blockIdx.x * 256 + threadIdx.x;  // over NN*32
    if (i < NN * 32) {
        float4 v = X[i];
        h4v o;
        o.x = (_Float16)v.x; o.y = (_Float16)v.y;
        o.z = (_Float16)v.z; o.w = (_Float16)v.w;
        O[i] = o;
    }
}

// ---------------- weight prep: fp32 [l][k][n] -> fp16 W^T [n][k] (single plane) ----
__global__ __launch_bounds__(256) void k_wprep(const float* __restrict__ W1,
                                               const float* __restrict__ W2,
                                               unsigned short* __restrict__ out) {
    int idx = blockIdx.x * 256 + threadIdx.x;  // over 3*2*16384
    if (idx >= 3 * 2 * 16384) return;
    int l = idx / (2 * 16384);
    int rem = idx % (2 * 16384);
    int mat = rem >> 14;
    int e = rem & 16383;
    int n = e >> 7, k = e & 127;
    const float* W = (mat == 0) ? (W1 + (size_t)l * 16384) : (W2 + (size_t)l * 16384);
    float v = W[k * 128 + n];
    _Float16* o = (_Float16*)out + (size_t)(l * 2 + mat) * 16384;
    o[n * 128 + k] = (_Float16)v;
}

// ---------------- weight prep for h0: Wcat^T (slot 6) + blockdiag(W2)^T (slot 7) ---
__global__ __launch_bounds__(256) void k_wprep_h0(const float* __restrict__ W1,  // [K,F,d]
                                                  const float* __restrict__ W2,  // [K,d,d]
                                                  unsigned short* __restrict__ out) {
    int idx = blockIdx.x * 256 + threadIdx.x;  // over 2*16384
    if (idx >= 2 * 16384) return;
    int mat = idx >> 14;
    int e = idx & 16383;
    int n = e >> 7, k = e & 127;
    float v;
    if (mat == 0) {
        v = W1[(n >> 4) * (FF * DD) + k * DD + (n & 15)];
    } else {
        v = ((k >> 4) == (n >> 4)) ? W2[(n >> 4) * 256 + (k & 15) * DD + (n & 15)] : 0.f;
    }
    _Float16* o = (_Float16*)out + (size_t)(6 + mat) * 16384;
    o[n * 128 + k] = (_Float16)v;
}

// ---------------- aggregation (R9: R6 layout + index prefetch, fp16 single plane) ---
template <bool BN, bool RELU>
__global__ __launch_bounds__(256) void k_agg(const h4v* __restrict__ X,
                                             const int* __restrict__ offs,
                                             const int* __restrict__ csr,
                                             const float* __restrict__ st,
                                             const float* __restrict__ g,
                                             const float* __restrict__ be,
                                             h4v* __restrict__ Zh) {
    int grp = threadIdx.x >> 5;
    int lane = threadIdx.x & 31;
    int n = blockIdx.x * 8 + grp;

    float4 a4 = make_float4(1.f, 1.f, 1.f, 1.f);
    float4 b4 = make_float4(0.f, 0.f, 0.f, 0.f);
    if (BN) bn_coefs(st, g, be, lane, a4, b4);

    auto apply = [&](float4 v) -> float4 {
        if (BN) {
            v.x = fmaf(v.x, a4.x, b4.x);
            v.y = fmaf(v.y, a4.y, b4.y);
            v.z = fmaf(v.z, a4.z, b4.z);
            v.w = fmaf(v.w, a4.w, b4.w);
        }
        if (RELU) {
            v.x = fmaxf(v.x, 0.f);
            v.y = fmaxf(v.y, 0.f);
            v.z = fmaxf(v.z, 0.f);
            v.w = fmaxf(v.w, 0.f);
        }
        return v;
    };
    auto add4 = [](float4& a, float4 b) {
        a.x += b.x; a.y += b.y; a.z += b.z; a.w += b.w;
    };

    float4 acc = apply(h2f(X[(size_t)n * 32 + lane]));
    int e0 = offs[n], e1 = offs[n + 1];
    int e = e0;
    int s0, s1, s2, s3, s4, s5, s6, s7;
    if (e + 8 <= e1) {
        s0 = csr[e]; s1 = csr[e + 1]; s2 = csr[e + 2]; s3 = csr[e + 3];
        s4 = csr[e + 4]; s5 = csr[e + 5]; s6 = csr[e + 6]; s7 = csr[e + 7];
    }
    while (e + 8 <= e1) {
        h4v r0 = X[(size_t)s0 * 32 + lane];
        h4v r1 = X[(size_t)s1 * 32 + lane];
        h4v r2 = X[(size_t)s2 * 32 + lane];
        h4v r3 = X[(size_t)s3 * 32 + lane];
        h4v r4 = X[(size_t)s4 * 32 + lane];
        h4v r5 = X[(size_t)s5 * 32 + lane];
        h4v r6 = X[(size_t)s6 * 32 + lane];
        h4v r7 = X[(size_t)s7 * 32 + lane];
        e += 8;
        // prefetch next batch's indices under this batch's accumulate
        int t0 = csr[e], t1 = csr[e + 1], t2 = csr[e + 2], t3 = csr[e + 3];
        int t4 = csr[e + 4], t5 = csr[e + 5], t6 = csr[e + 6], t7 = csr[e + 7];
        float4 v0 = apply(h2f(r0));
        float4 v1 = apply(h2f(r1));
        float4 v2 = apply(h2f(r2));
        float4 v3 = apply(h2f(r3));
        float4 v4 = apply(h2f(r4));
        float4 v5 = apply(h2f(r5));
        float4 v6 = apply(h2f(r6));
        float4 v7 = apply(h2f(r7));
        add4(v0, v1); add4(v2, v3); add4(v4, v5); add4(v6, v7);
        add4(v0, v2); add4(v4, v6); add4(v0, v4); add4(acc, v0);
        s0 = t0; s1 = t1; s2 = t2; s3 = t3;
        s4 = t4; s5 = t5; s6 = t6; s7 = t7;
    }
    for (; e + 4 <= e1; e += 4) {
        int q0 = csr[e], q1 = csr[e + 1], q2 = csr[e + 2], q3 = csr[e + 3];
        float4 v0 = apply(h2f(X[(size_t)q0 * 32 + lane]));
        float4 v1 = apply(h2f(X[(size_t)q1 * 32 + lane]));
        float4 v2 = apply(h2f(X[(size_t)q2 * 32 + lane]));
        float4 v3 = apply(h2f(X[(size_t)q3 * 32 + lane]));
        add4(v0, v1); add4(v2, v3); add4(v0, v2); add4(acc, v0);
    }
    for (; e < e1; e++) {
        float4 v = apply(h2f(X[(size_t)csr[e] * 32 + lane]));
        add4(acc, v);
    }
    h4v o;
    o.x = (_Float16)acc.x; o.y = (_Float16)acc.y;
    o.z = (_Float16)acc.z; o.w = (_Float16)acc.w;
    Zh[(size_t)n * 32 + lane] = o;
}

// ============ fp16 MFMA GEMM pair (R9, unchanged) ============
__global__ __launch_bounds__(256) void gemm_mfma(const _Float16* __restrict__ A,
                                                 const unsigned short* __restrict__ W1T,
                                                 const unsigned short* __restrict__ W2T,
                                                 const float* __restrict__ b1,
                                                 const float* __restrict__ b2,
                                                 _Float16* __restrict__ C,
                                                 float* __restrict__ stout) {
    __shared__ __align__(16) unsigned short Zs[8192];   // A/z fp16 [64][256B], 16KB
    __shared__ __align__(16) unsigned short Wch[8192];  // W chunk dbuf 2 x 8KB
    __shared__ float Sred[1024];                        // 4KB stats scratch
    int tid = threadIdx.x;
    int row0 = blockIdx.x * 64;
    int w = tid >> 6, lane = tid & 63, quad = lane >> 4, lid = lane & 15;

    // ---- per-thread W-stage source offsets (halfs, sans kc); 8KB chunk, 2/wave ----
    int wsrc[2], wdst[2];
#pragma unroll
    for (int i = 0; i < 2; i++) {
        int L = (w * 2 + i) * 1024 + lane * 16;  // byte within 8KB chunk image
        int npair = L >> 7, cc = L & 127;
        int ccp = cc ^ ((npair & 7) << 4);
        wsrc[i] = (npair * 2 + (ccp >> 6)) * 128 + ((ccp & 63) >> 1);
        wdst[i] = (w * 2 + i) * 1024;            // wave-uniform LDS byte base
    }

    // ---- stage A fp16 plane into Zs (global src pre-swizzled); 16KB, 4/wave ----
#pragma unroll
    for (int i = 0; i < 4; i++) {
        int L = (w * 4 + i) * 1024 + lane * 16;
        int row = L >> 8, cb = L & 255;
        int cbp = cb ^ ((row & 7) << 4);
        int grow = row0 + row;
        if (grow >= NN) grow = NN - 1;
        gload_lds16((const char*)A + (size_t)grow * 256 + cbp,
                    (char*)Zs + (w * 4 + i) * 1024);
    }
    // ---- stage W1 chunk 0 into buf 0 ----
#pragma unroll
    for (int i = 0; i < 2; i++)
        gload_lds16(W1T + wsrc[i], (char*)Wch + wdst[i]);
    __syncthreads();

    // ---- per-thread read-address precompute ----
    int lr = w * 16 + lid;
    int swzr = (lr & 7) << 4;
    int abase = lr * 256;  // byte within Zs
    int boff[8];
#pragma unroll
    for (int n0 = 0; n0 < 8; n0++) {
        int nn = n0 * 16 + lid;
        int cc = ((nn & 1) << 6) | (quad << 4);
        boff[n0] = (nn >> 1) * 128 + (cc ^ (((nn >> 1) & 7) << 4));
    }

    f4v acc[8];
#pragma unroll
    for (int i = 0; i < 8; i++) acc[i] = 0;

    // ---- unified 8-chunk loop: g 0..3 = phase 1 (W1), 4..7 = phase 2 (W2) ----
    for (int g = 0; g < 8; ++g) {
        int buf = g & 1;
        if (g < 7) {  // issue next chunk's stage first (overlaps with compute below)
            const unsigned short* WT = (g + 1 < 4) ? W1T : W2T;
            int kcn = (g + 1) & 3;
#pragma unroll
            for (int i = 0; i < 2; i++)
                gload_lds16(WT + wsrc[i] + kcn * 32,
                            (char*)Wch + (buf ^ 1) * 8192 + wdst[i]);
        }
        int kc = g & 3;
        int aoff = (kc * 64 + quad * 16) ^ swzr;
        h8v a = *(const h8v*)((const char*)Zs + abase + aoff);
        const char* wb = (const char*)Wch + buf * 8192;
#pragma unroll
        for (int n0 = 0; n0 < 8; n0++) {
            h8v b = *(const h8v*)(wb + boff[n0]);
            acc[n0] = __builtin_amdgcn_mfma_f32_16x16x32_f16(a, b, acc[n0], 0, 0, 0);
        }
        if (g == 3) {
            // z = relu(acc+b1) -> overwrite Zs (wave-local rows), same swizzled layout
#pragma unroll
            for (int n0 = 0; n0 < 8; n0++) {
                int c = n0 * 16 + lid;
                float bb = b1[c];
#pragma unroll
                for (int rr = 0; rr < 4; rr++) {
                    int zr = w * 16 + quad * 4 + rr;
                    float z = fmaxf(acc[n0][rr] + bb, 0.f);
                    int zb = zr * 256 + ((2 * c) ^ ((zr & 7) << 4));
                    *(_Float16*)((char*)Zs + zb) = (_Float16)z;
                }
                acc[n0] = 0;
            }
        }
        if (g < 7) __syncthreads();  // drains next-chunk stage; orders buffer reuse
    }

    // ---- epilogue: bias, fp16 store, stats (stats from fp32 register values) ----
#pragma unroll
    for (int n0 = 0; n0 < 8; n0++) {
        int c = n0 * 16 + lid;
        float bb = b2[c];
        float s = 0.f, q = 0.f;
#pragma unroll
        for (int rr = 0; rr < 4; rr++) {
            int grow = row0 + w * 16 + quad * 4 + rr;
            if (grow < NN) {
                float v = acc[n0][rr] + bb;
                C[(size_t)grow * 128 + c] = (_Float16)v;
                s += v;
                q += v * v;
            }
        }
        s += __shfl_xor(s, 16); s += __shfl_xor(s, 32);
        q += __shfl_xor(q, 16); q += __shfl_xor(q, 32);
        if (quad == 0) {
            Sred[w * 128 + c] = s;
            Sred[512 + w * 128 + c] = q;
        }
    }
    __syncthreads();
    if (tid < 128) {
        float s = Sred[tid] + Sred[128 + tid] + Sred[256 + tid] + Sred[384 + tid];
        float q = Sred[512 + tid] + Sred[640 + tid] + Sred[768 + tid] + Sred[896 + tid];
        atomicAdd(&stout[tid], s);
        atomicAdd(&stout[FF + tid], q);
    }
}

// ---------------- fused h1: agg + block-diag MLP + FUSED BN-stats (R12) ------------
// R12: final-layer stats computed from acc2 registers (shfl_xor(32) pair-merge,
// 4-wave LDS reduce, 1 atomicAdd/block) -> kills the k_stats 25.6MB re-read pass.
__global__ __launch_bounds__(256) void k_aggbd(const h4v* __restrict__ X,
                                               const int* __restrict__ offs,
                                               const int* __restrict__ csr,
                                               const float* __restrict__ st,
                                               const float* __restrict__ g,
                                               const float* __restrict__ be,
                                               const float* __restrict__ W1,
                                               const float4* __restrict__ b1,
                                               const float* __restrict__ W2,
                                               const float4* __restrict__ b2,
                                               float4* __restrict__ C,
                                               float* __restrict__ stout) {
    __shared__ float As[8][8 * BSTR];
    __shared__ float Ts[8][8 * BSTR];
    __shared__ float Ws1[KF * KSTR];
    __shared__ float Ws2[KF * KSTR];
    __shared__ float Sred[1024];  // 4KB: [2 planes][4 waves][128 cols]
    int grp = threadIdx.x >> 5, lane = threadIdx.x & 31;
    int n = blockIdx.x * 8 + grp;

    for (int l = threadIdx.x; l < KF * 256; l += 256) {
        int k = l >> 8, r = l & 255;
        Ws1[k * KSTR + r] = W1[l];
        Ws2[k * KSTR + r] = W2[l];
    }

    float4 a4, b4;
    bn_coefs(st, g, be, lane, a4, b4);
    auto apply = [&](float4 v) -> float4 {
        v.x = fmaxf(fmaf(v.x, a4.x, b4.x), 0.f);
        v.y = fmaxf(fmaf(v.y, a4.y, b4.y), 0.f);
        v.z = fmaxf(fmaf(v.z, a4.z, b4.z), 0.f);
        v.w = fmaxf(fmaf(v.w, a4.w, b4.w), 0.f);
        return v;
    };
    auto add4 = [](float4& a, float4 b) {
        a.x += b.x; a.y += b.y; a.z += b.z; a.w += b.w;
    };

    float4 acc = apply(h2f(X[(size_t)n * 32 + lane]));
    int e0 = offs[n], e1 = offs[n + 1];
    int e = e0;
    int s0, s1, s2, s3, s4, s5, s6, s7;
    if (e + 8 <= e1) {
        s0 = csr[e]; s1 = csr[e + 1]; s2 = csr[e + 2]; s3 = csr[e + 3];
        s4 = csr[e + 4]; s5 = csr[e + 5]; s6 = csr[e + 6]; s7 = csr[e + 7];
    }
    while (e + 8 <= e1) {
        h4v r0 = X[(size_t)s0 * 32 + lane];
        h4v r1 = X[(size_t)s1 * 32 + lane];
        h4v r2 = X[(size_t)s2 * 32 + lane];
        h4v r3 = X[(size_t)s3 * 32 + lane];
        h4v r4 = X[(size_t)s4 * 32 + lane];
        h4v r5 = X[(size_t)s5 * 32 + lane];
        h4v r6 = X[(size_t)s6 * 32 + lane];
        h4v r7 = X[(size_t)s7 * 32 + lane];
        e += 8;
        int t0 = csr[e], t1 = csr[e + 1], t2 = csr[e + 2], t3 = csr[e + 3];
        int t4 = csr[e + 4], t5 = csr[e + 5], t6 = csr[e + 6], t7 = csr[e + 7];
        float4 v0 = apply(h2f(r0));
        float4 v1 = apply(h2f(r1));
        float4 v2 = apply(h2f(r2));
        float4 v3 = apply(h2f(r3));
        float4 v4 = apply(h2f(r4));
        float4 v5 = apply(h2f(r5));
        float4 v6 = apply(h2f(r6));
        float4 v7 = apply(h2f(r7));
        add4(v0, v1); add4(v2, v3); add4(v4, v5); add4(v6, v7);
        add4(v0, v2); add4(v4, v6); add4(v0, v4); add4(acc, v0);
        s0 = t0; s1 = t1; s2 = t2; s3 = t3;
        s4 = t4; s5 = t5; s6 = t6; s7 = t7;
    }
    for (; e + 4 <= e1; e += 4) {
        int q0 = csr[e], q1 = csr[e + 1], q2 = csr[e + 2], q3 = csr[e + 3];
        float4 v0 = apply(h2f(X[(size_t)q0 * 32 + lane]));
        float4 v1 = apply(h2f(X[(size_t)q1 * 32 + lane]));
        float4 v2 = apply(h2f(X[(size_t)q2 * 32 + lane]));
        float4 v3 = apply(h2f(X[(size_t)q3 * 32 + lane]));
        add4(v0, v1); add4(v2, v3); add4(v0, v2); add4(acc, v0);
    }
    for (; e < e1; e++) {
        float4 v = apply(h2f(X[(size_t)csr[e] * 32 + lane]));
        add4(acc, v);
    }
    // store agg result (cols lane*4..+3) into padded layout
    *(float4*)&As[grp][(lane >> 2) * BSTR + (lane & 3) * 4] = acc;
    __syncthreads();

    int k = lane >> 2, jb = (lane & 3) * 4;
    float a[16];
    {
        const float4* As4 = (const float4*)&As[grp][k * BSTR];
        float4 a0 = As4[0], a1 = As4[1], a2 = As4[2], a3 = As4[3];
        a[0] = a0.x; a[1] = a0.y; a[2] = a0.z; a[3] = a0.w;
        a[4] = a1.x; a[5] = a1.y; a[6] = a1.z; a[7] = a1.w;
        a[8] = a2.x; a[9] = a2.y; a[10] = a2.z; a[11] = a2.w;
        a[12] = a3.x; a[13] = a3.y; a[14] = a3.z; a[15] = a3.w;
    }
    const float* wp1 = &Ws1[k * KSTR + jb];
    float4 t = b1[lane];
#pragma unroll
    for (int i = 0; i < 16; i++) {
        float4 wv = *(const float4*)&wp1[i * 16];
        t.x = fmaf(a[i], wv.x, t.x);
        t.y = fmaf(a[i], wv.y, t.y);
        t.z = fmaf(a[i], wv.z, t.z);
        t.w = fmaf(a[i], wv.w, t.w);
    }
    t.x = fmaxf(t.x, 0.f); t.y = fmaxf(t.y, 0.f);
    t.z = fmaxf(t.z, 0.f); t.w = fmaxf(t.w, 0.f);
    *(float4*)&Ts[grp][(lane >> 2) * BSTR + (lane & 3) * 4] = t;
    __syncthreads();

    float b[16];
    {
        const float4* Ts4 = (const float4*)&Ts[grp][k * BSTR];
        float4 a0 = Ts4[0], a1 = Ts4[1], a2 = Ts4[2], a3 = Ts4[3];
        b[0] = a0.x; b[1] = a0.y; b[2] = a0.z; b[3] = a0.w;
        b[4] = a1.x; b[5] = a1.y; b[6] = a1.z; b[7] = a1.w;
        b[8] = a2.x; b[9] = a2.y; b[10] = a2.z; b[11] = a2.w;
        b[12] = a3.x; b[13] = a3.y; b[14] = a3.z; b[15] = a3.w;
    }
    const float* wp2 = &Ws2[k * KSTR + jb];
    float4 acc2 = b2[lane];
#pragma unroll
    for (int i = 0; i < 16; i++) {
        float4 wv = *(const float4*)&wp2[i * 16];
        acc2.x = fmaf(b[i], wv.x, acc2.x);
        acc2.y = fmaf(b[i], wv.y, acc2.y);
        acc2.z = fmaf(b[i], wv.z, acc2.z);
        acc2.w = fmaf(b[i], wv.w, acc2.w);
    }
    C[(size_t)n * 32 + lane] = acc2;

    // ---- fused BN stats: grp pair-merge via shfl_xor(32), 4-wave LDS reduce ----
    float4 sq = make_float4(acc2.x * acc2.x, acc2.y * acc2.y,
                            acc2.z * acc2.z, acc2.w * acc2.w);
    acc2.x += __shfl_xor(acc2.x, 32); acc2.y += __shfl_xor(acc2.y, 32);
    acc2.z += __shfl_xor(acc2.z, 32); acc2.w += __shfl_xor(acc2.w, 32);
    sq.x += __shfl_xor(sq.x, 32); sq.y += __shfl_xor(sq.y, 32);
    sq.z += __shfl_xor(sq.z, 32); sq.w += __shfl_xor(sq.w, 32);
    int wv2 = threadIdx.x >> 6;
    if ((threadIdx.x & 63) < 32) {
        *(float4*)&Sred[wv2 * 128 + lane * 4] = acc2;
        *(float4*)&Sred[512 + wv2 * 128 + lane * 4] = sq;
    }
    __syncthreads();
    if (threadIdx.x < 128) {
        int c = threadIdx.x;
        float s = Sred[c] + Sred[128 + c] + Sred[256 + c] + Sred[384 + c];
        float q = Sred[512 + c] + Sred[640 + c] + Sred[768 + c] + Sred[896 + c];
        atomicAdd(&stout[c], s);
        atomicAdd(&stout[FF + c], q);
    }
}

// ---------------- pooling with fused final BN ----------------
__global__ __launch_bounds__(128) void k_pool(const float* __restrict__ X,
                                              const int* __restrict__ batch,
                                              const float* __restrict__ st,
                                              const float* __restrict__ g,
                                              const float* __restrict__ be,
                                              float* __restrict__ out) {
    int c = threadIdx.x;
    const float inv_n = 1.0f / (float)NN;
    float mu = st[c] * inv_n;
    float var = st[FF + c] * inv_n - mu * mu;
    float a = g[c] * rsqrtf(var + BN_EPS);
    float b = be[c] - mu * a;
    int chunk = (NN + gridDim.x - 1) / gridDim.x;
    int r0 = blockIdx.x * chunk;
    int r1 = min(r0 + chunk, NN);
    if (r0 >= r1) return;
    float acc = 0.f;
    int cnt = 0;
    int cur = batch[r0];
    for (int r = r0; r < r1; r++) {
        int bb = batch[r];
        if (bb != cur) {
            atomicAdd(&out[(size_t)cur * FF + c], fmaf(a, acc, b * (float)cnt));
            acc = 0.f;
            cnt = 0;
            cur = bb;
        }
        acc += X[(size_t)r * FF + c];
        cnt++;
    }
    atomicAdd(&out[(size_t)cur * FF + c], fmaf(a, acc, b * (float)cnt));
}

extern "C" void kernel_launch(void* const* d_in, const int* in_sizes, int n_in,
                              void* d_out, int out_size, void* d_ws, size_t ws_size,
                              hipStream_t stream) {
    const float* x = (const float*)d_in[0];
    const int* ei = (const int*)d_in[1];
    const int* src = ei;
    const int* dst = ei + NE;
    const int* batch = (const int*)d_in[2];
    const float* gc_W1 = (const float*)d_in[4];
    const float* gc_b1 = (const float*)d_in[5];
    const float* gc_W2 = (const float*)d_in[6];
    const float* gc_b2 = (const float*)d_in[7];
    const float* gc_g = (const float*)d_in[8];
    const float* gc_be = (const float*)d_in[9];
    const float* h0_W1 = (const float*)d_in[10];
    const float* h0_b1 = (const float*)d_in[11];
    const float* h0_W2 = (const float*)d_in[12];
    const float* h0_b2 = (const float*)d_in[13];
    const float* h0_g = (const float*)d_in[14];
    const float* h0_be = (const float*)d_in[15];
    const float* h1_W1 = (const float*)d_in[16];
    const float* h1_b1 = (const float*)d_in[17];
    const float* h1_W2 = (const float*)d_in[18];
    const float* h1_b2 = (const float*)d_in[19];
    const float* h1_g = (const float*)d_in[20];
    const float* h1_be = (const float*)d_in[21];

    const size_t NF = (size_t)NN * FF;
    float* P0 = (float*)d_ws;  // Zh fp16 plane (k_agg output / gemm A input)
    float* P1 = P0 + NF;       // Hbuf fp16 (gemm C output / gather input)
    float* P2 = P1 + NF;       // k_aggbd fp32 output
    float* stats = P2 + NF;
    int* deg = (int*)(stats + 5 * 256);
    int* cnt = deg + NN;
    int* offs = cnt + NN;
    int* bsum = offs + (NN + 4);
    int* boffs = bsum + 256;
    int* csr = boffs + 256;
    unsigned short* wbf = (unsigned short*)(csr + NE);  // 8 slots x 16384 fp16

    h4v* Zh = (h4v*)P0;    // fp16 agg output, NN x 128
    h4v* Hbuf = (h4v*)P1;  // fp16 activations, NN x 128

    hipMemsetAsync(deg, 0, (size_t)2 * NN * sizeof(int), stream);
    hipMemsetAsync(stats, 0, 5 * 256 * sizeof(float), stream);
    hipMemsetAsync(d_out, 0, (size_t)GG * KF * DD * sizeof(float), stream);

    k_deg<<<(NE + 255) / 256, 256, 0, stream>>>(dst, deg);
    k_bsum<<<NB, 256, 0, stream>>>(deg, bsum);
    k_bscan<<<1, 256, 0, stream>>>(bsum, boffs);
    k_offs<<<NB, 256, 0, stream>>>(deg, boffs, offs);
    k_fill<<<(NE + 255) / 256, 256, 0, stream>>>(src, dst, offs, cnt, csr);
    k_wprep<<<(3 * 2 * 16384 + 255) / 256, 256, 0, stream>>>(gc_W1, gc_W2, wbf);
    k_wprep_h0<<<(2 * 16384 + 255) / 256, 256, 0, stream>>>(h0_W1, h0_W2, wbf);
    k_cvt<<<(NN * 32 + 255) / 256, 256, 0, stream>>>((const float4*)x, Hbuf);

    const int agg_grid = NN / 8;            // 6250
    const int gemm_grid = (NN + 63) / 64;   // 782

    // ---- GC layers: agg(fp16 out) + fp16 MFMA gemm pair (stats fused) ----
    k_agg<false, false><<<agg_grid, 256, 0, stream>>>(
        Hbuf, offs, csr, nullptr, nullptr, nullptr, Zh);
    gemm_mfma<<<gemm_grid, 256, 0, stream>>>(
        (const _Float16*)Zh, wbf + 0 * 16384, wbf + 1 * 16384, gc_b1, gc_b2,
        (_Float16*)Hbuf, stats);

    k_agg<true, true><<<agg_grid, 256, 0, stream>>>(
        Hbuf, offs, csr, stats, gc_g, gc_be, Zh);
    gemm_mfma<<<gemm_grid, 256, 0, stream>>>(
        (const _Float16*)Zh, wbf + 2 * 16384, wbf + 3 * 16384, gc_b1 + FF, gc_b2 + FF,
        (_Float16*)Hbuf, stats + 256);

    k_agg<true, true><<<agg_grid, 256, 0, stream>>>(
        Hbuf, offs, csr, stats + 256, gc_g + FF, gc_be + FF, Zh);
    gemm_mfma<<<gemm_grid, 256, 0, stream>>>(
        (const _Float16*)Zh, wbf + 4 * 16384, wbf + 5 * 16384, gc_b1 + 2 * FF, gc_b2 + 2 * FF,
        (_Float16*)Hbuf, stats + 512);

    // ---- head layer 0: agg (GC2 BN, no relu) + fp16 MFMA (Wcat + blockdiag) ----
    k_agg<true, false><<<agg_grid, 256, 0, stream>>>(
        Hbuf, offs, csr, stats + 512, gc_g + 2 * FF, gc_be + 2 * FF, Zh);
    gemm_mfma<<<gemm_grid, 256, 0, stream>>>(
        (const _Float16*)Zh, wbf + 6 * 16384, wbf + 7 * 16384, h0_b1, h0_b2,
        (_Float16*)Hbuf, stats + 768);

    // ---- head layer 1: fused agg(BN+relu) + block-diag MLP + fused stats ----
    k_aggbd<<<agg_grid, 256, 0, stream>>>(
        Hbuf, offs, csr, stats + 768, h0_g, h0_be,
        h1_W1, (const float4*)h1_b1, h1_W2, (const float4*)h1_b2, (float4*)P2,
        stats + 1024);

    // ---- pool with fused final BN ----
    k_pool<<<512, 128, 0, stream>>>(P2, batch, stats + 1024, h1_g, h1_be, (float*)d_out);
}

// Round 13
// 572.216 us; speedup vs baseline: 1.1988x; 1.1482x over previous
//
#include <hip/hip_runtime.h>

#define NN 50000
#define NE 800000
#define FF 128
#define KF 8
#define DD 16
#define GG 512
#define BN_EPS 1e-5f
#define NB 196   // ceil(NN/256)
#define KSTR 264 // padded k-block stride for block-diag weights (flat staging)
#define BSTR 20  // padded per-16-col block stride (floats) in aggbd As/Ts

using s8v = __attribute__((ext_vector_type(8))) short;
using f4v = __attribute__((ext_vector_type(4))) float;
using h4v = __attribute__((ext_vector_type(4))) _Float16;
using h8v = __attribute__((ext_vector_type(8))) _Float16;
typedef unsigned int u32;

// async global->LDS, 16B per lane; LDS dest = wave-uniform base + lane*16 (m104),
// global src is PER-LANE (m173) -> swizzled layouts via pre-swizzled source address.
__device__ __forceinline__ void gload_lds16(const void* g, void* l) {
    __builtin_amdgcn_global_load_lds((const __attribute__((address_space(1))) u32*)g,
                                     (__attribute__((address_space(3))) u32*)l, 16, 0, 0);
}

// ---------------- CSR build ----------------
__global__ void k_deg(const int* __restrict__ dst, int* __restrict__ deg) {
    int e = blockIdx.x * 256 + threadIdx.x;
    if (e < NE) atomicAdd(&deg[dst[e]], 1);
}

__global__ __launch_bounds__(256) void k_bsum(const int* __restrict__ deg, int* __restrict__ bsum) {
    int idx = blockIdx.x * 256 + threadIdx.x;
    int v = (idx < NN) ? deg[idx] : 0;
#pragma unroll
    for (int off = 32; off; off >>= 1) v += __shfl_down(v, off, 64);
    __shared__ int ws[4];
    if ((threadIdx.x & 63) == 0) ws[threadIdx.x >> 6] = v;
    __syncthreads();
    if (threadIdx.x == 0) bsum[blockIdx.x] = ws[0] + ws[1] + ws[2] + ws[3];
}

__global__ __launch_bounds__(256) void k_bscan(const int* __restrict__ bsum, int* __restrict__ boffs) {
    __shared__ int s[256];
    int tid = threadIdx.x;
    int v = (tid < NB) ? bsum[tid] : 0;
    s[tid] = v;
    __syncthreads();
    for (int off = 1; off < 256; off <<= 1) {
        int t = (tid >= off) ? s[tid - off] : 0;
        __syncthreads();
        s[tid] += t;
        __syncthreads();
    }
    if (tid < NB) boffs[tid] = s[tid] - v;  // exclusive
}

__global__ __launch_bounds__(256) void k_offs(const int* __restrict__ deg,
                                              const int* __restrict__ boffs,
                                              int* __restrict__ offs) {
    __shared__ int s[256];
    int tid = threadIdx.x;
    int idx = blockIdx.x * 256 + tid;
    int v = (idx < NN) ? deg[idx] : 0;
    s[tid] = v;
    __syncthreads();
    for (int off = 1; off < 256; off <<= 1) {
        int t = (tid >= off) ? s[tid - off] : 0;
        __syncthreads();
        s[tid] += t;
        __syncthreads();
    }
    int incl = s[tid];
    if (idx < NN) offs[idx] = boffs[blockIdx.x] + incl - v;
    if (idx == NN - 1) offs[NN] = boffs[blockIdx.x] + incl;
}

__global__ void k_fill(const int* __restrict__ src, const int* __restrict__ dst,
                       const int* __restrict__ offs, int* __restrict__ cnt,
                       int* __restrict__ csr) {
    int e = blockIdx.x * 256 + threadIdx.x;
    if (e < NE) {
        int d = dst[e];
        int p = atomicAdd(&cnt[d], 1);
        csr[offs[d] + p] = src[e];
    }
}

// ---------------- helpers ----------------
__device__ __forceinline__ void bn_coefs(const float* st, const float* g, const float* be,
                                         int lane, float4& a4, float4& b4) {
    const float inv_n = 1.0f / (float)NN;
    float av[4], bv[4];
#pragma unroll
    for (int t = 0; t < 4; t++) {
        int c = lane * 4 + t;
        float mu = st[c] * inv_n;
        float var = st[FF + c] * inv_n - mu * mu;
        float a = g[c] * rsqrtf(var + BN_EPS);
        av[t] = a;
        bv[t] = be[c] - mu * a;
    }
    a4 = make_float4(av[0], av[1], av[2], av[3]);
    b4 = make_float4(bv[0], bv[1], bv[2], bv[3]);
}

__device__ __forceinline__ float4 h2f(h4v h) {
    return make_float4((float)h.x, (float)h.y, (float)h.z, (float)h.w);
}

// ---------------- fp32 -> fp16 one-shot convert of the input x ----------------
__global__ __launch_bounds__(256) void k_cvt(const float4* __restrict__ X, h4v* __restrict__ O) {
    int i = blockIdx.x * 256 + threadIdx.x;  // over NN*32
    if (i < NN * 32) {
        float4 v = X[i];
        h4v o;
        o.x = (_Float16)v.x; o.y = (_Float16)v.y;
        o.z = (_Float16)v.z; o.w = (_Float16)v.w;
        O[i] = o;
    }
}

// ---------------- weight prep: fp32 [l][k][n] -> fp16 W^T [n][k] (single plane) ----
__global__ __launch_bounds__(256) void k_wprep(const float* __restrict__ W1,
                                               const float* __restrict__ W2,
                                               unsigned short* __restrict__ out) {
    int idx = blockIdx.x * 256 + threadIdx.x;  // over 3*2*16384
    if (idx >= 3 * 2 * 16384) return;
    int l = idx / (2 * 16384);
    int rem = idx % (2 * 16384);
    int mat = rem >> 14;
    int e = rem & 16383;
    int n = e >> 7, k = e & 127;
    const float* W = (mat == 0) ? (W1 + (size_t)l * 16384) : (W2 + (size_t)l * 16384);
    float v = W[k * 128 + n];
    _Float16* o = (_Float16*)out + (size_t)(l * 2 + mat) * 16384;
    o[n * 128 + k] = (_Float16)v;
}

// ---------------- weight prep for h0: Wcat^T (slot 6) + blockdiag(W2)^T (slot 7) ---
__global__ __launch_bounds__(256) void k_wprep_h0(const float* __restrict__ W1,  // [K,F,d]
                                                  const float* __restrict__ W2,  // [K,d,d]
                                                  unsigned short* __restrict__ out) {
    int idx = blockIdx.x * 256 + threadIdx.x;  // over 2*16384
    if (idx >= 2 * 16384) return;
    int mat = idx >> 14;
    int e = idx & 16383;
    int n = e >> 7, k = e & 127;
    float v;
    if (mat == 0) {
        v = W1[(n >> 4) * (FF * DD) + k * DD + (n & 15)];
    } else {
        v = ((k >> 4) == (n >> 4)) ? W2[(n >> 4) * 256 + (k & 15) * DD + (n & 15)] : 0.f;
    }
    _Float16* o = (_Float16*)out + (size_t)(6 + mat) * 16384;
    o[n * 128 + k] = (_Float16)v;
}

// ---------------- aggregation (R9: R6 layout + index prefetch, fp16 single plane) ---
template <bool BN, bool RELU>
__global__ __launch_bounds__(256) void k_agg(const h4v* __restrict__ X,
                                             const int* __restrict__ offs,
                                             const int* __restrict__ csr,
                                             const float* __restrict__ st,
                                             const float* __restrict__ g,
                                             const float* __restrict__ be,
                                             h4v* __restrict__ Zh) {
    int grp = threadIdx.x >> 5;
    int lane = threadIdx.x & 31;
    int n = blockIdx.x * 8 + grp;

    float4 a4 = make_float4(1.f, 1.f, 1.f, 1.f);
    float4 b4 = make_float4(0.f, 0.f, 0.f, 0.f);
    if (BN) bn_coefs(st, g, be, lane, a4, b4);

    auto apply = [&](float4 v) -> float4 {
        if (BN) {
            v.x = fmaf(v.x, a4.x, b4.x);
            v.y = fmaf(v.y, a4.y, b4.y);
            v.z = fmaf(v.z, a4.z, b4.z);
            v.w = fmaf(v.w, a4.w, b4.w);
        }
        if (RELU) {
            v.x = fmaxf(v.x, 0.f);
            v.y = fmaxf(v.y, 0.f);
            v.z = fmaxf(v.z, 0.f);
            v.w = fmaxf(v.w, 0.f);
        }
        return v;
    };
    auto add4 = [](float4& a, float4 b) {
        a.x += b.x; a.y += b.y; a.z += b.z; a.w += b.w;
    };

    float4 acc = apply(h2f(X[(size_t)n * 32 + lane]));
    int e0 = offs[n], e1 = offs[n + 1];
    int e = e0;
    int s0, s1, s2, s3, s4, s5, s6, s7;
    if (e + 8 <= e1) {
        s0 = csr[e]; s1 = csr[e + 1]; s2 = csr[e + 2]; s3 = csr[e + 3];
        s4 = csr[e + 4]; s5 = csr[e + 5]; s6 = csr[e + 6]; s7 = csr[e + 7];
    }
    while (e + 8 <= e1) {
        h4v r0 = X[(size_t)s0 * 32 + lane];
        h4v r1 = X[(size_t)s1 * 32 + lane];
        h4v r2 = X[(size_t)s2 * 32 + lane];
        h4v r3 = X[(size_t)s3 * 32 + lane];
        h4v r4 = X[(size_t)s4 * 32 + lane];
        h4v r5 = X[(size_t)s5 * 32 + lane];
        h4v r6 = X[(size_t)s6 * 32 + lane];
        h4v r7 = X[(size_t)s7 * 32 + lane];
        e += 8;
        // prefetch next batch's indices under this batch's accumulate
        int t0 = csr[e], t1 = csr[e + 1], t2 = csr[e + 2], t3 = csr[e + 3];
        int t4 = csr[e + 4], t5 = csr[e + 5], t6 = csr[e + 6], t7 = csr[e + 7];
        float4 v0 = apply(h2f(r0));
        float4 v1 = apply(h2f(r1));
        float4 v2 = apply(h2f(r2));
        float4 v3 = apply(h2f(r3));
        float4 v4 = apply(h2f(r4));
        float4 v5 = apply(h2f(r5));
        float4 v6 = apply(h2f(r6));
        float4 v7 = apply(h2f(r7));
        add4(v0, v1); add4(v2, v3); add4(v4, v5); add4(v6, v7);
        add4(v0, v2); add4(v4, v6); add4(v0, v4); add4(acc, v0);
        s0 = t0; s1 = t1; s2 = t2; s3 = t3;
        s4 = t4; s5 = t5; s6 = t6; s7 = t7;
    }
    for (; e + 4 <= e1; e += 4) {
        int q0 = csr[e], q1 = csr[e + 1], q2 = csr[e + 2], q3 = csr[e + 3];
        float4 v0 = apply(h2f(X[(size_t)q0 * 32 + lane]));
        float4 v1 = apply(h2f(X[(size_t)q1 * 32 + lane]));
        float4 v2 = apply(h2f(X[(size_t)q2 * 32 + lane]));
        float4 v3 = apply(h2f(X[(size_t)q3 * 32 + lane]));
        add4(v0, v1); add4(v2, v3); add4(v0, v2); add4(acc, v0);
    }
    for (; e < e1; e++) {
        float4 v = apply(h2f(X[(size_t)csr[e] * 32 + lane]));
        add4(acc, v);
    }
    h4v o;
    o.x = (_Float16)acc.x; o.y = (_Float16)acc.y;
    o.z = (_Float16)acc.z; o.w = (_Float16)acc.w;
    Zh[(size_t)n * 32 + lane] = o;
}

// ============ fp16 MFMA GEMM pair (R9, unchanged) ============
__global__ __launch_bounds__(256) void gemm_mfma(const _Float16* __restrict__ A,
                                                 const unsigned short* __restrict__ W1T,
                                                 const unsigned short* __restrict__ W2T,
                                                 const float* __restrict__ b1,
                                                 const float* __restrict__ b2,
                                                 _Float16* __restrict__ C,
                                                 float* __restrict__ stout) {
    __shared__ __align__(16) unsigned short Zs[8192];   // A/z fp16 [64][256B], 16KB
    __shared__ __align__(16) unsigned short Wch[8192];  // W chunk dbuf 2 x 8KB
    __shared__ float Sred[1024];                        // 4KB stats scratch
    int tid = threadIdx.x;
    int row0 = blockIdx.x * 64;
    int w = tid >> 6, lane = tid & 63, quad = lane >> 4, lid = lane & 15;

    // ---- per-thread W-stage source offsets (halfs, sans kc); 8KB chunk, 2/wave ----
    int wsrc[2], wdst[2];
#pragma unroll
    for (int i = 0; i < 2; i++) {
        int L = (w * 2 + i) * 1024 + lane * 16;  // byte within 8KB chunk image
        int npair = L >> 7, cc = L & 127;
        int ccp = cc ^ ((npair & 7) << 4);
        wsrc[i] = (npair * 2 + (ccp >> 6)) * 128 + ((ccp & 63) >> 1);
        wdst[i] = (w * 2 + i) * 1024;            // wave-uniform LDS byte base
    }

    // ---- stage A fp16 plane into Zs (global src pre-swizzled); 16KB, 4/wave ----
#pragma unroll
    for (int i = 0; i < 4; i++) {
        int L = (w * 4 + i) * 1024 + lane * 16;
        int row = L >> 8, cb = L & 255;
        int cbp = cb ^ ((row & 7) << 4);
        int grow = row0 + row;
        if (grow >= NN) grow = NN - 1;
        gload_lds16((const char*)A + (size_t)grow * 256 + cbp,
                    (char*)Zs + (w * 4 + i) * 1024);
    }
    // ---- stage W1 chunk 0 into buf 0 ----
#pragma unroll
    for (int i = 0; i < 2; i++)
        gload_lds16(W1T + wsrc[i], (char*)Wch + wdst[i]);
    __syncthreads();

    // ---- per-thread read-address precompute ----
    int lr = w * 16 + lid;
    int swzr = (lr & 7) << 4;
    int abase = lr * 256;  // byte within Zs
    int boff[8];
#pragma unroll
    for (int n0 = 0; n0 < 8; n0++) {
        int nn = n0 * 16 + lid;
        int cc = ((nn & 1) << 6) | (quad << 4);
        boff[n0] = (nn >> 1) * 128 + (cc ^ (((nn >> 1) & 7) << 4));
    }

    f4v acc[8];
#pragma unroll
    for (int i = 0; i < 8; i++) acc[i] = 0;

    // ---- unified 8-chunk loop: g 0..3 = phase 1 (W1), 4..7 = phase 2 (W2) ----
    for (int g = 0; g < 8; ++g) {
        int buf = g & 1;
        if (g < 7) {  // issue next chunk's stage first (overlaps with compute below)
            const unsigned short* WT = (g + 1 < 4) ? W1T : W2T;
            int kcn = (g + 1) & 3;
#pragma unroll
            for (int i = 0; i < 2; i++)
                gload_lds16(WT + wsrc[i] + kcn * 32,
                            (char*)Wch + (buf ^ 1) * 8192 + wdst[i]);
        }
        int kc = g & 3;
        int aoff = (kc * 64 + quad * 16) ^ swzr;
        h8v a = *(const h8v*)((const char*)Zs + abase + aoff);
        const char* wb = (const char*)Wch + buf * 8192;
#pragma unroll
        for (int n0 = 0; n0 < 8; n0++) {
            h8v b = *(const h8v*)(wb + boff[n0]);
            acc[n0] = __builtin_amdgcn_mfma_f32_16x16x32_f16(a, b, acc[n0], 0, 0, 0);
        }
        if (g == 3) {
            // z = relu(acc+b1) -> overwrite Zs (wave-local rows), same swizzled layout
#pragma unroll
            for (int n0 = 0; n0 < 8; n0++) {
                int c = n0 * 16 + lid;
                float bb = b1[c];
#pragma unroll
                for (int rr = 0; rr < 4; rr++) {
                    int zr = w * 16 + quad * 4 + rr;
                    float z = fmaxf(acc[n0][rr] + bb, 0.f);
                    int zb = zr * 256 + ((2 * c) ^ ((zr & 7) << 4));
                    *(_Float16*)((char*)Zs + zb) = (_Float16)z;
                }
                acc[n0] = 0;
            }
        }
        if (g < 7) __syncthreads();  // drains next-chunk stage; orders buffer reuse
    }

    // ---- epilogue: bias, fp16 store, stats (stats from fp32 register values) ----
#pragma unroll
    for (int n0 = 0; n0 < 8; n0++) {
        int c = n0 * 16 + lid;
        float bb = b2[c];
        float s = 0.f, q = 0.f;
#pragma unroll
        for (int rr = 0; rr < 4; rr++) {
            int grow = row0 + w * 16 + quad * 4 + rr;
            if (grow < NN) {
                float v = acc[n0][rr] + bb;
                C[(size_t)grow * 128 + c] = (_Float16)v;
                s += v;
                q += v * v;
            }
        }
        s += __shfl_xor(s, 16); s += __shfl_xor(s, 32);
        q += __shfl_xor(q, 16); q += __shfl_xor(q, 32);
        if (quad == 0) {
            Sred[w * 128 + c] = s;
            Sred[512 + w * 128 + c] = q;
        }
    }
    __syncthreads();
    if (tid < 128) {
        float s = Sred[tid] + Sred[128 + tid] + Sred[256 + tid] + Sred[384 + tid];
        float q = Sred[512 + tid] + Sred[640 + tid] + Sred[768 + tid] + Sred[896 + tid];
        atomicAdd(&stout[tid], s);
        atomicAdd(&stout[FF + tid], q);
    }
}

// ---------------- fused h1: agg (R9) + block-diag MLP, fp16 output (R13) -----------
__global__ __launch_bounds__(256) void k_aggbd(const h4v* __restrict__ X,
                                               const int* __restrict__ offs,
                                               const int* __restrict__ csr,
                                               const float* __restrict__ st,
                                               const float* __restrict__ g,
                                               const float* __restrict__ be,
                                               const float* __restrict__ W1,
                                               const float4* __restrict__ b1,
                                               const float* __restrict__ W2,
                                               const float4* __restrict__ b2,
                                               h4v* __restrict__ C) {
    __shared__ float As[8][8 * BSTR];
    __shared__ float Ts[8][8 * BSTR];
    __shared__ float Ws1[KF * KSTR];
    __shared__ float Ws2[KF * KSTR];
    int grp = threadIdx.x >> 5, lane = threadIdx.x & 31;
    int n = blockIdx.x * 8 + grp;

    for (int l = threadIdx.x; l < KF * 256; l += 256) {
        int k = l >> 8, r = l & 255;
        Ws1[k * KSTR + r] = W1[l];
        Ws2[k * KSTR + r] = W2[l];
    }

    float4 a4, b4;
    bn_coefs(st, g, be, lane, a4, b4);
    auto apply = [&](float4 v) -> float4 {
        v.x = fmaxf(fmaf(v.x, a4.x, b4.x), 0.f);
        v.y = fmaxf(fmaf(v.y, a4.y, b4.y), 0.f);
        v.z = fmaxf(fmaf(v.z, a4.z, b4.z), 0.f);
        v.w = fmaxf(fmaf(v.w, a4.w, b4.w), 0.f);
        return v;
    };
    auto add4 = [](float4& a, float4 b) {
        a.x += b.x; a.y += b.y; a.z += b.z; a.w += b.w;
    };

    float4 acc = apply(h2f(X[(size_t)n * 32 + lane]));
    int e0 = offs[n], e1 = offs[n + 1];
    int e = e0;
    int s0, s1, s2, s3, s4, s5, s6, s7;
    if (e + 8 <= e1) {
        s0 = csr[e]; s1 = csr[e + 1]; s2 = csr[e + 2]; s3 = csr[e + 3];
        s4 = csr[e + 4]; s5 = csr[e + 5]; s6 = csr[e + 6]; s7 = csr[e + 7];
    }
    while (e + 8 <= e1) {
        h4v r0 = X[(size_t)s0 * 32 + lane];
        h4v r1 = X[(size_t)s1 * 32 + lane];
        h4v r2 = X[(size_t)s2 * 32 + lane];
        h4v r3 = X[(size_t)s3 * 32 + lane];
        h4v r4 = X[(size_t)s4 * 32 + lane];
        h4v r5 = X[(size_t)s5 * 32 + lane];
        h4v r6 = X[(size_t)s6 * 32 + lane];
        h4v r7 = X[(size_t)s7 * 32 + lane];
        e += 8;
        int t0 = csr[e], t1 = csr[e + 1], t2 = csr[e + 2], t3 = csr[e + 3];
        int t4 = csr[e + 4], t5 = csr[e + 5], t6 = csr[e + 6], t7 = csr[e + 7];
        float4 v0 = apply(h2f(r0));
        float4 v1 = apply(h2f(r1));
        float4 v2 = apply(h2f(r2));
        float4 v3 = apply(h2f(r3));
        float4 v4 = apply(h2f(r4));
        float4 v5 = apply(h2f(r5));
        float4 v6 = apply(h2f(r6));
        float4 v7 = apply(h2f(r7));
        add4(v0, v1); add4(v2, v3); add4(v4, v5); add4(v6, v7);
        add4(v0, v2); add4(v4, v6); add4(v0, v4); add4(acc, v0);
        s0 = t0; s1 = t1; s2 = t2; s3 = t3;
        s4 = t4; s5 = t5; s6 = t6; s7 = t7;
    }
    for (; e + 4 <= e1; e += 4) {
        int q0 = csr[e], q1 = csr[e + 1], q2 = csr[e + 2], q3 = csr[e + 3];
        float4 v0 = apply(h2f(X[(size_t)q0 * 32 + lane]));
        float4 v1 = apply(h2f(X[(size_t)q1 * 32 + lane]));
        float4 v2 = apply(h2f(X[(size_t)q2 * 32 + lane]));
        float4 v3 = apply(h2f(X[(size_t)q3 * 32 + lane]));
        add4(v0, v1); add4(v2, v3); add4(v0, v2); add4(acc, v0);
    }
    for (; e < e1; e++) {
        float4 v = apply(h2f(X[(size_t)csr[e] * 32 + lane]));
        add4(acc, v);
    }
    // store agg result (cols lane*4..+3) into padded layout
    *(float4*)&As[grp][(lane >> 2) * BSTR + (lane & 3) * 4] = acc;
    __syncthreads();

    int k = lane >> 2, jb = (lane & 3) * 4;
    float a[16];
    {
        const float4* As4 = (const float4*)&As[grp][k * BSTR];
        float4 a0 = As4[0], a1 = As4[1], a2 = As4[2], a3 = As4[3];
        a[0] = a0.x; a[1] = a0.y; a[2] = a0.z; a[3] = a0.w;
        a[4] = a1.x; a[5] = a1.y; a[6] = a1.z; a[7] = a1.w;
        a[8] = a2.x; a[9] = a2.y; a[10] = a2.z; a[11] = a2.w;
        a[12] = a3.x; a[13] = a3.y; a[14] = a3.z; a[15] = a3.w;
    }
    const float* wp1 = &Ws1[k * KSTR + jb];
    float4 t = b1[lane];
#pragma unroll
    for (int i = 0; i < 16; i++) {
        float4 wv = *(const float4*)&wp1[i * 16];
        t.x = fmaf(a[i], wv.x, t.x);
        t.y = fmaf(a[i], wv.y, t.y);
        t.z = fmaf(a[i], wv.z, t.z);
        t.w = fmaf(a[i], wv.w, t.w);
    }
    t.x = fmaxf(t.x, 0.f); t.y = fmaxf(t.y, 0.f);
    t.z = fmaxf(t.z, 0.f); t.w = fmaxf(t.w, 0.f);
    *(float4*)&Ts[grp][(lane >> 2) * BSTR + (lane & 3) * 4] = t;
    __syncthreads();

    float b[16];
    {
        const float4* Ts4 = (const float4*)&Ts[grp][k * BSTR];
        float4 a0 = Ts4[0], a1 = Ts4[1], a2 = Ts4[2], a3 = Ts4[3];
        b[0] = a0.x; b[1] = a0.y; b[2] = a0.z; b[3] = a0.w;
        b[4] = a1.x; b[5] = a1.y; b[6] = a1.z; b[7] = a1.w;
        b[8] = a2.x; b[9] = a2.y; b[10] = a2.z; b[11] = a2.w;
        b[12] = a3.x; b[13] = a3.y; b[14] = a3.z; b[15] = a3.w;
    }
    const float* wp2 = &Ws2[k * KSTR + jb];
    float4 acc2 = b2[lane];
#pragma unroll
    for (int i = 0; i < 16; i++) {
        float4 wv = *(const float4*)&wp2[i * 16];
        acc2.x = fmaf(b[i], wv.x, acc2.x);
        acc2.y = fmaf(b[i], wv.y, acc2.y);
        acc2.z = fmaf(b[i], wv.z, acc2.z);
        acc2.w = fmaf(b[i], wv.w, acc2.w);
    }
    h4v o;
    o.x = (_Float16)acc2.x; o.y = (_Float16)acc2.y;
    o.z = (_Float16)acc2.z; o.w = (_Float16)acc2.w;
    C[(size_t)n * 32 + lane] = o;
}

// ---------------- BN stats (standalone, fp16 input) ----------------
__global__ __launch_bounds__(256) void k_stats(const _Float16* __restrict__ X,
                                               float* __restrict__ st, int nrows) {
    int c = threadIdx.x & 127;
    int half = threadIdx.x >> 7;
    int rpb = (nrows + gridDim.x - 1) / gridDim.x;
    int r0 = blockIdx.x * rpb;
    int r1 = min(r0 + rpb, nrows);
    float s = 0.f, sq = 0.f;
    for (int r = r0 + half; r < r1; r += 2) {
        float v = (float)X[(size_t)r * FF + c];
        s += v;
        sq += v * v;
    }
    atomicAdd(&st[c], s);
    atomicAdd(&st[FF + c], sq);
}

// ---------------- pooling with fused final BN (fp16 input) ----------------
__global__ __launch_bounds__(128) void k_pool(const _Float16* __restrict__ X,
                                              const int* __restrict__ batch,
                                              const float* __restrict__ st,
                                              const float* __restrict__ g,
                                              const float* __restrict__ be,
                                              float* __restrict__ out) {
    int c = threadIdx.x;
    const float inv_n = 1.0f / (float)NN;
    float mu = st[c] * inv_n;
    float var = st[FF + c] * inv_n - mu * mu;
    float a = g[c] * rsqrtf(var + BN_EPS);
    float b = be[c] - mu * a;
    int chunk = (NN + gridDim.x - 1) / gridDim.x;
    int r0 = blockIdx.x * chunk;
    int r1 = min(r0 + chunk, NN);
    if (r0 >= r1) return;
    float acc = 0.f;
    int cnt = 0;
    int cur = batch[r0];
    for (int r = r0; r < r1; r++) {
        int bb = batch[r];
        if (bb != cur) {
            atomicAdd(&out[(size_t)cur * FF + c], fmaf(a, acc, b * (float)cnt));
            acc = 0.f;
            cnt = 0;
            cur = bb;
        }
        acc += (float)X[(size_t)r * FF + c];
        cnt++;
    }
    atomicAdd(&out[(size_t)cur * FF + c], fmaf(a, acc, b * (float)cnt));
}

extern "C" void kernel_launch(void* const* d_in, const int* in_sizes, int n_in,
                              void* d_out, int out_size, void* d_ws, size_t ws_size,
                              hipStream_t stream) {
    const float* x = (const float*)d_in[0];
    const int* ei = (const int*)d_in[1];
    const int* src = ei;
    const int* dst = ei + NE;
    const int* batch = (const int*)d_in[2];
    const float* gc_W1 = (const float*)d_in[4];
    const float* gc_b1 = (const float*)d_in[5];
    const float* gc_W2 = (const float*)d_in[6];
    const float* gc_b2 = (const float*)d_in[7];
    const float* gc_g = (const float*)d_in[8];
    const float* gc_be = (const float*)d_in[9];
    const float* h0_W1 = (const float*)d_in[10];
    const float* h0_b1 = (const float*)d_in[11];
    const float* h0_W2 = (const float*)d_in[12];
    const float* h0_b2 = (const float*)d_in[13];
    const float* h0_g = (const float*)d_in[14];
    const float* h0_be = (const float*)d_in[15];
    const float* h1_W1 = (const float*)d_in[16];
    const float* h1_b1 = (const float*)d_in[17];
    const float* h1_W2 = (const float*)d_in[18];
    const float* h1_b2 = (const float*)d_in[19];
    const float* h1_g = (const float*)d_in[20];
    const float* h1_be = (const float*)d_in[21];

    const size_t NF = (size_t)NN * FF;
    float* P0 = (float*)d_ws;  // Zh fp16 plane (k_agg output / gemm A input)
    float* P1 = P0 + NF;       // Hbuf fp16 (gemm C output / gather input)
    float* P2 = P1 + NF;       // k_aggbd fp16 output
    float* stats = P2 + NF;
    int* deg = (int*)(stats + 5 * 256);
    int* cnt = deg + NN;
    int* offs = cnt + NN;
    int* bsum = offs + (NN + 4);
    int* boffs = bsum + 256;
    int* csr = boffs + 256;
    unsigned short* wbf = (unsigned short*)(csr + NE);  // 8 slots x 16384 fp16

    h4v* Zh = (h4v*)P0;    // fp16 agg output, NN x 128
    h4v* Hbuf = (h4v*)P1;  // fp16 activations, NN x 128

    hipMemsetAsync(deg, 0, (size_t)2 * NN * sizeof(int), stream);
    hipMemsetAsync(stats, 0, 5 * 256 * sizeof(float), stream);
    hipMemsetAsync(d_out, 0, (size_t)GG * KF * DD * sizeof(float), stream);

    k_deg<<<(NE + 255) / 256, 256, 0, stream>>>(dst, deg);
    k_bsum<<<NB, 256, 0, stream>>>(deg, bsum);
    k_bscan<<<1, 256, 0, stream>>>(bsum, boffs);
    k_offs<<<NB, 256, 0, stream>>>(deg, boffs, offs);
    k_fill<<<(NE + 255) / 256, 256, 0, stream>>>(src, dst, offs, cnt, csr);
    k_wprep<<<(3 * 2 * 16384 + 255) / 256, 256, 0, stream>>>(gc_W1, gc_W2, wbf);
    k_wprep_h0<<<(2 * 16384 + 255) / 256, 256, 0, stream>>>(h0_W1, h0_W2, wbf);
    k_cvt<<<(NN * 32 + 255) / 256, 256, 0, stream>>>((const float4*)x, Hbuf);

    const int agg_grid = NN / 8;            // 6250
    const int gemm_grid = (NN + 63) / 64;   // 782

    // ---- GC layers: agg(fp16 out) + fp16 MFMA gemm pair (stats fused) ----
    k_agg<false, false><<<agg_grid, 256, 0, stream>>>(
        Hbuf, offs, csr, nullptr, nullptr, nullptr, Zh);
    gemm_mfma<<<gemm_grid, 256, 0, stream>>>(
        (const _Float16*)Zh, wbf + 0 * 16384, wbf + 1 * 16384, gc_b1, gc_b2,
        (_Float16*)Hbuf, stats);

    k_agg<true, true><<<agg_grid, 256, 0, stream>>>(
        Hbuf, offs, csr, stats, gc_g, gc_be, Zh);
    gemm_mfma<<<gemm_grid, 256, 0, stream>>>(
        (const _Float16*)Zh, wbf + 2 * 16384, wbf + 3 * 16384, gc_b1 + FF, gc_b2 + FF,
        (_Float16*)Hbuf, stats + 256);

    k_agg<true, true><<<agg_grid, 256, 0, stream>>>(
        Hbuf, offs, csr, stats + 256, gc_g + FF, gc_be + FF, Zh);
    gemm_mfma<<<gemm_grid, 256, 0, stream>>>(
        (const _Float16*)Zh, wbf + 4 * 16384, wbf + 5 * 16384, gc_b1 + 2 * FF, gc_b2 + 2 * FF,
        (_Float16*)Hbuf, stats + 512);

    // ---- head layer 0: agg (GC2 BN, no relu) + fp16 MFMA (Wcat + blockdiag) ----
    k_agg<true, false><<<agg_grid, 256, 0, stream>>>(
        Hbuf, offs, csr, stats + 512, gc_g + 2 * FF, gc_be + 2 * FF, Zh);
    gemm_mfma<<<gemm_grid, 256, 0, stream>>>(
        (const _Float16*)Zh, wbf + 6 * 16384, wbf + 7 * 16384, h0_b1, h0_b2,
        (_Float16*)Hbuf, stats + 768);

    // ---- head layer 1: fused agg(BN+relu) + double block-diag MLP (fp16 out) ----
    k_aggbd<<<agg_grid, 256, 0, stream>>>(
        Hbuf, offs, csr, stats + 768, h0_g, h0_be,
        h1_W1, (const float4*)h1_b1, h1_W2, (const float4*)h1_b2, (h4v*)P2);
    k_stats<<<256, 256, 0, stream>>>((const _Float16*)P2, stats + 1024, NN);

    // ---- pool with fused final BN ----
    k_pool<<<512, 128, 0, stream>>>((const _Float16*)P2, batch, stats + 1024, h1_g, h1_be,
                                    (float*)d_out);
}